// Round 23
// baseline (375.667 us; speedup 1.0000x reference)
//
#include <hip/hip_runtime.h>
#include <hip/hip_bf16.h>

#define B_    16
#define C_    96
#define H_    224
#define W_    224
#define COUT_ 96
#define GH_   14
#define GW_   14
#define P_    196          // GH_*GW_
#define HW_   (H_*W_)      // 50176
#define NCH_  12           // 8-channel chunks
#define APITCH 181         // A-tile plane pitch in px

#define AS1 __attribute__((address_space(1)))
#define AS3 __attribute__((address_space(3)))

typedef __attribute__((ext_vector_type(8))) unsigned short ushort8;
typedef __attribute__((ext_vector_type(8))) short        short8;   // MFMA bf16x8 operand
typedef __attribute__((ext_vector_type(4))) float        f32x4;

__device__ __forceinline__ unsigned short f2bf(float f) {
    union { __hip_bfloat16 h; unsigned short u; } cv;
    cv.h = __float2bfloat16(f);
    return cv.u;
}

// ---------------------------------------------------------------------------
// Kernel 1 (merged): blocks [0, 3136) = per-patch depthwise 3x3 -> sa
// (float4-vectorized x staging, R22); tail blocks = filter repack -> ofb3
// (fragment order) + zero-page.
// ---------------------------------------------------------------------------
__global__ __launch_bounds__(256) void sa_prep_kernel(const float* __restrict__ x,
                                                      const float* __restrict__ pf,
                                                      unsigned short* __restrict__ sa,
                                                      const float* __restrict__ of,
                                                      unsigned short* __restrict__ ofb3,
                                                      unsigned short* __restrict__ zp) {
    int bid = blockIdx.x;

    if (bid >= B_ * P_) {                  // ---- prep tail: ofb3 + zp ----
        int pb = bid - B_ * P_;
        if (pb == 0 && threadIdx.x < 128) zp[threadIdx.x] = 0;
        int e = pb * 256 + threadIdx.x;    // 9*3*6*64*8 = 82944
        if (e < 82944) {
            int j    = e & 7;
            int l    = (e >> 3) & 63;
            int ni   = (e >> 9) % 6;
            int cs   = (e / 3072) % 3;
            int tap  = e / 9216;
            int cout = ni * 16 + (l & 15);
            int c    = cs * 32 + (l >> 4) * 8 + j;
            ofb3[e] = f2bf(of[((size_t)cout * 96 + c) * 9 + tap]);
        }
        return;
    }

    // ---- sa part ----
    int patch = bid % P_;
    int b     = bid / P_;
    int gh = patch / GW_, gw = patch % GW_;
    int t  = threadIdx.x;
    int py = t >> 4, px = t & 15;
    int y  = gh * 16 + py, xx = gw * 16 + px;

    __shared__ f32x4 xs4[2][8][64];    // 16 KB double-buffered x slice (f32x4 view)

    const float* xbase = x + (size_t)(b * 96) * HW_ + (size_t)(gh * 16) * W_ + gw * 16;
    int ch0 = t >> 6, r0 = t & 63;
    int ch1 = (t + 256) >> 6, r1 = (t + 256) & 63;
    const float* g0 = xbase + (size_t)(r0 >> 2) * W_ + (r0 & 3) * 4;
    const float* g1 = xbase + (size_t)(r1 >> 2) * W_ + (r1 & 3) * 4;

    f32x4 lfA, lfB;
    lfA = *(const f32x4*)(g0 + (size_t)ch0 * HW_);
    lfB = *(const f32x4*)(g1 + (size_t)ch1 * HW_);

    for (int cc = 0; cc < NCH_; ++cc) {
        int buf = cc & 1;
        xs4[buf][ch0][r0] = lfA;
        xs4[buf][ch1][r1] = lfB;
        __syncthreads();
        if (cc < NCH_ - 1) {
            lfA = *(const f32x4*)(g0 + (size_t)((cc + 1) * 8 + ch0) * HW_);
            lfB = *(const f32x4*)(g1 + (size_t)((cc + 1) * 8 + ch1) * HW_);
        }

        const float* xsf = (const float*)&xs4[buf][0][0];   // [8][256] f32 view
        ushort8 v;
        #pragma unroll
        for (int ch = 0; ch < 8; ++ch) {
            const float* wgt = pf + ((size_t)(cc * 8 + ch) * P_ + patch) * 9;  // uniform -> s_load
            float a = 0.f;
            #pragma unroll
            for (int dy = -1; dy <= 1; ++dy) {
                int yy = py + dy;
                if ((unsigned)yy < 16u) {
                    #pragma unroll
                    for (int dx = -1; dx <= 1; ++dx) {
                        int xq = px + dx;
                        if ((unsigned)xq < 16u)
                            a = fmaf(xsf[ch * 256 + yy * 16 + xq],
                                     wgt[(dy + 1) * 3 + (dx + 1)], a);
                    }
                }
            }
            v[ch] = f2bf(a);
        }
        *(ushort8*)&sa[(((size_t)(b * NCH_ + cc) * H_ + y) * W_ + xx) * 8] = v;
    }
}

// ---------------------------------------------------------------------------
// Kernel 2: implicit-GEMM MFMA conv + exact GELU, half-patch blocks.
// R23 = R19's lean loop (af inline, VGPR 64) at 4 blocks/CU:
//   - launch_bounds(256,4): unified budget 128/wave = 48 acc + 64 arch + 16
//     margin (R7's spill case was acc=96; this fits);
//   - LDS 36,864 x 4 = 147 KB <= 160 KB -> 4 blocks/CU = 4 waves/SIMD,
//     the next notch on the measured occupancy ladder (2->3 was +20 us);
//   - bf depth-1 fence pipeline kept (R17, +22 us); af-prefetch dropped
//     (R20: null for +16 VGPR / -8% occupancy).
// ---------------------------------------------------------------------------
__global__ __launch_bounds__(256, 4) void conv2_mfma(const unsigned short* __restrict__ sa,
                                                     const unsigned short* __restrict__ ofb3,
                                                     const unsigned short* __restrict__ zp,
                                                     float* __restrict__ out) {
    // XCD-aware swizzle (6272 % 8 == 0 -> bijective); same-patch halves adjacent
    int bid0 = blockIdx.x;
    int bid  = (bid0 % 8) * (6272 / 8) + bid0 / 8;
    int half = bid & 1;
    int pid  = bid >> 1;
    int patch = pid % P_;
    int b     = pid / P_;
    int gh = patch / GW_, gw = patch % GW_;
    int y0 = gh * 16 + half * 8, x0 = gw * 16;   // 8x16 output region

    int t = threadIdx.x;
    int w = t >> 6, l = t & 63;
    int wm = w & 1, wn = w >> 1;            // 2 M-waves x 2 N-waves
    int mrow = l & 15, kgrp = l >> 4;

    __shared__ ushort8 at8[2304];           // 12 planes x 181 slots (+132 trash) = 36,864 B

    // ---- single staging burst: 10x18 halo, plane-major, 181-slot pitch ----
    #pragma unroll
    for (int i = 0; i < 9; ++i) {
        int v = t + i * 256;                // 0..2303; real: v<2172 && slot<180
        const unsigned short* src = zp;
        if (v < 2172) {
            int ccl = v / APITCH, hpx = v - ccl * APITCH;
            if (hpx < 180) {
                int gy = y0 - 1 + hpx / 18, gx = x0 - 1 + hpx % 18;
                if ((unsigned)gy < (unsigned)H_ && (unsigned)gx < (unsigned)W_)
                    src = &sa[(((size_t)(b * NCH_ + ccl) * H_ + gy) * W_ + gx) * 8];
            }
        }
        __builtin_amdgcn_global_load_lds((const AS1 unsigned int*)src,
                                         (AS3 unsigned int*)&at8[v], 16, 0, 0);
    }

    f32x4 acc[4][3];
    #pragma unroll
    for (int mi = 0; mi < 4; ++mi)
        #pragma unroll
        for (int ni = 0; ni < 3; ++ni)
            acc[mi][ni] = (f32x4)0.f;

    __syncthreads();                        // drain DMA; tile visible; queue EMPTY

    const unsigned short* at = (const unsigned short*)at8;  // [plane][181 px][8ch]

    // bf fetch for step T (tap = T/3, cs = T%3); wave wn's 3 couts-of-16
    short8 bfA[3], bfB[3];
    auto LOADBF = [&](short8* dst, int T) {
        const unsigned short* p = ofb3 + (size_t)(T / 3) * 9216 + (T % 3) * 3072
                                  + (wn * 3) * 512 + l * 8;
        #pragma unroll
        for (int nj = 0; nj < 3; ++nj)
            dst[nj] = *(const short8*)&p[nj * 512];
    };

    LOADBF(bfA, 0);
    #pragma unroll                          // full unroll: bfA/bfB static (rule #20)
    for (int T = 0; T < 27; ++T) {
        short8* cur = (T & 1) ? bfB : bfA;
        short8* nxt = (T & 1) ? bfA : bfB;
        if (T + 1 < 27) LOADBF(nxt, T + 1); // issue-early (T14)
        __builtin_amdgcn_sched_barrier(0);  // pin loads above the MFMA burst

        int tap = T / 3, cs = T % 3;
        int ky = tap / 3, kx = tap % 3;
        #pragma unroll
        for (int mi = 0; mi < 4; ++mi) {
            short8 af = *(const short8*)&at[((cs * 4 + kgrp) * APITCH
                                            + (wm * 4 + mi + ky) * 18
                                            + kx + mrow) * 8];
            #pragma unroll
            for (int nj = 0; nj < 3; ++nj)
                acc[mi][nj] = __builtin_amdgcn_mfma_f32_16x16x32_bf16(
                    af, cur[nj], acc[mi][nj], 0, 0, 0);
        }
    }

    // ---- epilogue: exact GELU + f32x4 stores ----
    #pragma unroll
    for (int mi = 0; mi < 4; ++mi) {
        int gy = y0 + wm * 4 + mi;
        #pragma unroll
        for (int nj = 0; nj < 3; ++nj) {
            int cout = (wn * 3 + nj) * 16 + mrow;
            f32x4 gv;
            #pragma unroll
            for (int j = 0; j < 4; ++j) {
                float vv = acc[mi][nj][j];
                gv[j] = 0.5f * vv * (1.0f + erff(vv * 0.70710678118f));
            }
            *(f32x4*)&out[((size_t)b * COUT_ + cout) * HW_ + (size_t)gy * W_ +
                          x0 + kgrp * 4] = gv;
        }
    }
}

extern "C" void kernel_launch(void* const* d_in, const int* in_sizes, int n_in,
                              void* d_out, int out_size, void* d_ws, size_t ws_size,
                              hipStream_t stream) {
    const float* x  = (const float*)d_in[0];
    const float* pf = (const float*)d_in[1];
    const float* of = (const float*)d_in[2];
    float* out = (float*)d_out;

    unsigned short* sa   = (unsigned short*)d_ws;                       // 154,140,672 B
    unsigned short* ofb3 = (unsigned short*)((char*)d_ws + 154140672);  // + 165,888 B
    unsigned short* zp   = (unsigned short*)((char*)d_ws + 154306560);  // + 256 B zero-page

    sa_prep_kernel<<<B_ * P_ + 324, 256, 0, stream>>>(x, pf, sa, of, ofb3, zp);
    conv2_mfma<<<B_ * P_ * 2, 256, 0, stream>>>(sa, ofb3, zp, out);
}

// Round 24
// 362.879 us; speedup vs baseline: 1.0352x; 1.0352x over previous
//
#include <hip/hip_runtime.h>
#include <hip/hip_bf16.h>

#define B_    16
#define C_    96
#define H_    224
#define W_    224
#define COUT_ 96
#define GH_   14
#define GW_   14
#define P_    196          // GH_*GW_
#define HW_   (H_*W_)      // 50176
#define NCH_  12           // 8-channel chunks
#define APITCH 181         // A-tile plane pitch in px

#define AS1 __attribute__((address_space(1)))
#define AS3 __attribute__((address_space(3)))

typedef __attribute__((ext_vector_type(8))) unsigned short ushort8;
typedef __attribute__((ext_vector_type(8))) short        short8;   // MFMA bf16x8 operand
typedef __attribute__((ext_vector_type(4))) float        f32x4;

__device__ __forceinline__ unsigned short f2bf(float f) {
    union { __hip_bfloat16 h; unsigned short u; } cv;
    cv.h = __float2bfloat16(f);
    return cv.u;
}

// ---------------------------------------------------------------------------
// Kernel 1 (merged): blocks [0, 3136) = per-patch depthwise 3x3 -> sa
// (float4-vectorized x staging); tail blocks = filter repack -> ofb3
// (fragment order) + zero-page. (R22-proven, unchanged.)
// ---------------------------------------------------------------------------
__global__ __launch_bounds__(256) void sa_prep_kernel(const float* __restrict__ x,
                                                      const float* __restrict__ pf,
                                                      unsigned short* __restrict__ sa,
                                                      const float* __restrict__ of,
                                                      unsigned short* __restrict__ ofb3,
                                                      unsigned short* __restrict__ zp) {
    int bid = blockIdx.x;

    if (bid >= B_ * P_) {                  // ---- prep tail: ofb3 + zp ----
        int pb = bid - B_ * P_;
        if (pb == 0 && threadIdx.x < 128) zp[threadIdx.x] = 0;
        int e = pb * 256 + threadIdx.x;    // 9*3*6*64*8 = 82944
        if (e < 82944) {
            int j    = e & 7;
            int l    = (e >> 3) & 63;
            int ni   = (e >> 9) % 6;
            int cs   = (e / 3072) % 3;
            int tap  = e / 9216;
            int cout = ni * 16 + (l & 15);
            int c    = cs * 32 + (l >> 4) * 8 + j;
            ofb3[e] = f2bf(of[((size_t)cout * 96 + c) * 9 + tap]);
        }
        return;
    }

    // ---- sa part ----
    int patch = bid % P_;
    int b     = bid / P_;
    int gh = patch / GW_, gw = patch % GW_;
    int t  = threadIdx.x;
    int py = t >> 4, px = t & 15;
    int y  = gh * 16 + py, xx = gw * 16 + px;

    __shared__ f32x4 xs4[2][8][64];    // 16 KB double-buffered x slice (f32x4 view)

    const float* xbase = x + (size_t)(b * 96) * HW_ + (size_t)(gh * 16) * W_ + gw * 16;
    int ch0 = t >> 6, r0 = t & 63;
    int ch1 = (t + 256) >> 6, r1 = (t + 256) & 63;
    const float* g0 = xbase + (size_t)(r0 >> 2) * W_ + (r0 & 3) * 4;
    const float* g1 = xbase + (size_t)(r1 >> 2) * W_ + (r1 & 3) * 4;

    f32x4 lfA, lfB;
    lfA = *(const f32x4*)(g0 + (size_t)ch0 * HW_);
    lfB = *(const f32x4*)(g1 + (size_t)ch1 * HW_);

    for (int cc = 0; cc < NCH_; ++cc) {
        int buf = cc & 1;
        xs4[buf][ch0][r0] = lfA;
        xs4[buf][ch1][r1] = lfB;
        __syncthreads();
        if (cc < NCH_ - 1) {
            lfA = *(const f32x4*)(g0 + (size_t)((cc + 1) * 8 + ch0) * HW_);
            lfB = *(const f32x4*)(g1 + (size_t)((cc + 1) * 8 + ch1) * HW_);
        }

        const float* xsf = (const float*)&xs4[buf][0][0];   // [8][256] f32 view
        ushort8 v;
        #pragma unroll
        for (int ch = 0; ch < 8; ++ch) {
            const float* wgt = pf + ((size_t)(cc * 8 + ch) * P_ + patch) * 9;  // uniform -> s_load
            float a = 0.f;
            #pragma unroll
            for (int dy = -1; dy <= 1; ++dy) {
                int yy = py + dy;
                if ((unsigned)yy < 16u) {
                    #pragma unroll
                    for (int dx = -1; dx <= 1; ++dx) {
                        int xq = px + dx;
                        if ((unsigned)xq < 16u)
                            a = fmaf(xsf[ch * 256 + yy * 16 + xq],
                                     wgt[(dy + 1) * 3 + (dx + 1)], a);
                    }
                }
            }
            v[ch] = f2bf(a);
        }
        *(ushort8*)&sa[(((size_t)(b * NCH_ + cc) * H_ + y) * W_ + xx) * 8] = v;
    }
}

// ---------------------------------------------------------------------------
// Kernel 2: implicit-GEMM MFMA conv + exact GELU, half-patch blocks.
// R24 = R19 structure + ROLLING af REGISTER CACHE (halved LDS traffic):
//   Diagnosis: per-CU LDS read pipe ~70% busy (12 waves x 108 ds_read_b128
//   x ~12 cyc vs ~22k cyc block lifetime) -- the shared-resource wall that
//   made occupancy 3->4 (R23) and af-prefetch (R20) null.
//   Fix: cs-outer / tap-inner loop with afc[6 rows][3 kx] register cache.
//   Rows are reused across the 3 ky values (rows wm*4+mi+ky overlap), so
//   per cs: 12 preload + 3 per extra ky = 18 ds_reads vs 36 -> LDS-pipe
//   busy ~35%. All afc indices compile-time (full unroll, rule #20).
//   bf: R17's depth-1 fence pipeline, reordered T = cs*9 + tap.
//   Occupancy (256,3) = measured-best 3 blocks/CU. Peak live regs ~152
//   (60 afc + 24 bf + 48 acc + addr) < 168 budget; tripwire = WRITE_SIZE.
// ---------------------------------------------------------------------------
__global__ __launch_bounds__(256, 3) void conv2_mfma(const unsigned short* __restrict__ sa,
                                                     const unsigned short* __restrict__ ofb3,
                                                     const unsigned short* __restrict__ zp,
                                                     float* __restrict__ out) {
    // XCD-aware swizzle (6272 % 8 == 0 -> bijective); same-patch halves adjacent
    int bid0 = blockIdx.x;
    int bid  = (bid0 % 8) * (6272 / 8) + bid0 / 8;
    int half = bid & 1;
    int pid  = bid >> 1;
    int patch = pid % P_;
    int b     = pid / P_;
    int gh = patch / GW_, gw = patch % GW_;
    int y0 = gh * 16 + half * 8, x0 = gw * 16;   // 8x16 output region

    int t = threadIdx.x;
    int w = t >> 6, l = t & 63;
    int wm = w & 1, wn = w >> 1;            // 2 M-waves x 2 N-waves
    int mrow = l & 15, kgrp = l >> 4;

    __shared__ ushort8 at8[2304];           // 12 planes x 181 slots (+132 trash) = 36,864 B

    // ---- single staging burst: 10x18 halo, plane-major, 181-slot pitch ----
    #pragma unroll
    for (int i = 0; i < 9; ++i) {
        int v = t + i * 256;                // 0..2303; real: v<2172 && slot<180
        const unsigned short* src = zp;
        if (v < 2172) {
            int ccl = v / APITCH, hpx = v - ccl * APITCH;
            if (hpx < 180) {
                int gy = y0 - 1 + hpx / 18, gx = x0 - 1 + hpx % 18;
                if ((unsigned)gy < (unsigned)H_ && (unsigned)gx < (unsigned)W_)
                    src = &sa[(((size_t)(b * NCH_ + ccl) * H_ + gy) * W_ + gx) * 8];
            }
        }
        __builtin_amdgcn_global_load_lds((const AS1 unsigned int*)src,
                                         (AS3 unsigned int*)&at8[v], 16, 0, 0);
    }

    f32x4 acc[4][3];
    #pragma unroll
    for (int mi = 0; mi < 4; ++mi)
        #pragma unroll
        for (int ni = 0; ni < 3; ++ni)
            acc[mi][ni] = (f32x4)0.f;

    __syncthreads();                        // drain DMA; tile visible; queue EMPTY

    const unsigned short* at = (const unsigned short*)at8;  // [plane][181 px][8ch]

    // af fragment read: plane cs*4+kgrp, halo row wm*4+r, col shift kx
    auto LDAF = [&](int cs, int r, int kx) {
        return *(const short8*)&at[((cs * 4 + kgrp) * APITCH
                                    + (wm * 4 + r) * 18 + kx + mrow) * 8];
    };
    // bf fetch for step T (cs = T/9, tap = T%9); wave wn's 3 couts-of-16
    short8 bfA[3], bfB[3];
    auto LOADBF = [&](short8* dst, int T) {
        int cs = T / 9, tap = T % 9;
        const unsigned short* p = ofb3 + (size_t)tap * 9216 + cs * 3072
                                  + (wn * 3) * 512 + l * 8;
        #pragma unroll
        for (int nj = 0; nj < 3; ++nj)
            dst[nj] = *(const short8*)&p[nj * 512];
    };

    short8 afc[6][3];                       // rolling row cache (static idx only)

    LOADBF(bfA, 0);
    #pragma unroll                          // FULL unroll incl. cs: ring + afc static
    for (int cs = 0; cs < 3; ++cs) {
        #pragma unroll
        for (int r = 0; r < 4; ++r)         // preload rows 0..3, all 3 shifts
            #pragma unroll
            for (int kx = 0; kx < 3; ++kx)
                afc[r][kx] = LDAF(cs, r, kx);

        #pragma unroll
        for (int ky = 0; ky < 3; ++ky) {
            if (ky > 0) {                   // roll window: one new row (3 shifts)
                #pragma unroll
                for (int kx = 0; kx < 3; ++kx)
                    afc[3 + ky][kx] = LDAF(cs, 3 + ky, kx);
            }
            #pragma unroll
            for (int kx = 0; kx < 3; ++kx) {
                int T = cs * 9 + ky * 3 + kx;
                short8* cur = (T & 1) ? bfB : bfA;
                short8* nxt = (T & 1) ? bfA : bfB;
                if (T + 1 < 27) LOADBF(nxt, T + 1);  // issue-early (T14)
                __builtin_amdgcn_sched_barrier(0);   // pin issues above the burst

                #pragma unroll
                for (int mi = 0; mi < 4; ++mi)
                    #pragma unroll
                    for (int nj = 0; nj < 3; ++nj)
                        acc[mi][nj] = __builtin_amdgcn_mfma_f32_16x16x32_bf16(
                            afc[mi + ky][kx], cur[nj], acc[mi][nj], 0, 0, 0);
            }
        }
    }

    // ---- epilogue: exact GELU + f32x4 stores ----
    #pragma unroll
    for (int mi = 0; mi < 4; ++mi) {
        int gy = y0 + wm * 4 + mi;
        #pragma unroll
        for (int nj = 0; nj < 3; ++nj) {
            int cout = (wn * 3 + nj) * 16 + mrow;
            f32x4 gv;
            #pragma unroll
            for (int j = 0; j < 4; ++j) {
                float vv = acc[mi][nj][j];
                gv[j] = 0.5f * vv * (1.0f + erff(vv * 0.70710678118f));
            }
            *(f32x4*)&out[((size_t)b * COUT_ + cout) * HW_ + (size_t)gy * W_ +
                          x0 + kgrp * 4] = gv;
        }
    }
}

extern "C" void kernel_launch(void* const* d_in, const int* in_sizes, int n_in,
                              void* d_out, int out_size, void* d_ws, size_t ws_size,
                              hipStream_t stream) {
    const float* x  = (const float*)d_in[0];
    const float* pf = (const float*)d_in[1];
    const float* of = (const float*)d_in[2];
    float* out = (float*)d_out;

    unsigned short* sa   = (unsigned short*)d_ws;                       // 154,140,672 B
    unsigned short* ofb3 = (unsigned short*)((char*)d_ws + 154140672);  // + 165,888 B
    unsigned short* zp   = (unsigned short*)((char*)d_ws + 154306560);  // + 256 B zero-page

    sa_prep_kernel<<<B_ * P_ + 324, 256, 0, stream>>>(x, pf, sa, of, ofb3, zp);
    conv2_mfma<<<B_ * P_ * 2, 256, 0, stream>>>(sa, ofb3, zp, out);
}